// Round 7
// baseline (246.967 us; speedup 1.0000x reference)
//
#include <hip/hip_runtime.h>
#include <hip/hip_bf16.h>

// Problem constants
#define Bq 32
#define Lq 256
#define Hq 8
#define Eq 16
#define Nn (Bq*Hq)        // 256 sequences
#define T 254             // Lq - 3 + 1
#define A 145             // E + 1 + 128 augmented channels
#define SIG_CH (A + A*A)  // 21170
#define KP 21184          // padded K (mult of 32), bf16 arrays
#define OUT 256
#define TPAD 256          // aug_t row stride (t dimension)

typedef __attribute__((ext_vector_type(8))) short short8;
typedef __attribute__((ext_vector_type(8))) unsigned short ushort8;
typedef __attribute__((ext_vector_type(4))) float floatx4;

static __device__ __forceinline__ unsigned short f2bf(float v) {
    unsigned int u = __float_as_uint(v);
    unsigned int r = (u + 0x7FFFu + ((u >> 16) & 1u)) >> 16;
    return (unsigned short)r;
}
static __device__ __forceinline__ float bf2f(unsigned short b) {
    return __uint_as_float(((unsigned int)b) << 16);
}

// ---------------------------------------------------------------------------
// Kernel A: conv1(k=3,16->64) -> conv2(k=1,64->128)+ReLU.
// Output TRANSPOSED: aug_t[n][ch][t], t contiguous (TPAD=256).
// grid (4, 256), 256 threads. All LDS reads are ds_read_b128 (i-vectorized).
// ---------------------------------------------------------------------------
__global__ __launch_bounds__(256) void aug_kernel(
    const float* __restrict__ q,
    const float* __restrict__ w1, const float* __restrict__ b1,
    const float* __restrict__ w2, const float* __restrict__ b2,
    float* __restrict__ aug_t)
{
    __shared__ __align__(16) float w1s[48*64];
    __shared__ __align__(16) float w2s[64*128];
    __shared__ __align__(16) float b1s[64];
    __shared__ __align__(16) float b2s[128];
    __shared__ __align__(16) float xs[68*16];
    __shared__ __align__(16) float a1s[32*64];

    const int tid = threadIdx.x;
    const int n = blockIdx.y;
    const int b = n >> 3, h = n & 7;
    const int tb0 = blockIdx.x * 64;

    for (int i = tid; i < 48*64; i += 256) w1s[i] = w1[i];
    for (int i = tid; i < 64*128; i += 256) w2s[i] = w2[i];
    if (tid < 64)  b1s[tid] = b1[tid];
    if (tid < 128) b2s[tid] = b2[tid];
    {
        const float4* q4 = (const float4*)q + ((long)(b*Lq)*Hq + h)*4;
        float4* xs4 = (float4*)xs;
        for (int i = tid; i < 68*4; i += 256) {
            int rr = i >> 2, e4 = i & 3;
            int t = tb0 + rr; if (t > 255) t = 255;
            xs4[rr*4 + e4] = q4[t*32 + e4];
        }
    }
    __syncthreads();

    const float inv253 = 1.0f / 253.0f;

    #pragma unroll
    for (int sub = 0; sub < 2; ++sub) {
        const int t0 = tb0 + sub*32;
        const int l0 = sub*32;

        // ---- conv1: thread owns c quad + 2 t rows. All reads b128.
        {
            const int c = (tid & 15) * 4;
            const int tg = tid >> 4;
            float4 bb = *(const float4*)&b1s[c];
            float4 acc0 = bb, acc1 = bb;
            #pragma unroll
            for (int dt = 0; dt < 3; ++dt) {
                #pragma unroll
                for (int i4 = 0; i4 < 4; ++i4) {
                    float4 xa = *(const float4*)&xs[(l0 + tg + dt)*16 + i4*4];
                    float4 xb = *(const float4*)&xs[(l0 + tg + 16 + dt)*16 + i4*4];
                    float4 w0 = *(const float4*)&w1s[(dt*16 + i4*4 + 0)*64 + c];
                    float4 w1v = *(const float4*)&w1s[(dt*16 + i4*4 + 1)*64 + c];
                    float4 w2v = *(const float4*)&w1s[(dt*16 + i4*4 + 2)*64 + c];
                    float4 w3 = *(const float4*)&w1s[(dt*16 + i4*4 + 3)*64 + c];
                    acc0.x += xa.x*w0.x + xa.y*w1v.x + xa.z*w2v.x + xa.w*w3.x;
                    acc0.y += xa.x*w0.y + xa.y*w1v.y + xa.z*w2v.y + xa.w*w3.y;
                    acc0.z += xa.x*w0.z + xa.y*w1v.z + xa.z*w2v.z + xa.w*w3.z;
                    acc0.w += xa.x*w0.w + xa.y*w1v.w + xa.z*w2v.w + xa.w*w3.w;
                    acc1.x += xb.x*w0.x + xb.y*w1v.x + xb.z*w2v.x + xb.w*w3.x;
                    acc1.y += xb.x*w0.y + xb.y*w1v.y + xb.z*w2v.y + xb.w*w3.y;
                    acc1.z += xb.x*w0.z + xb.y*w1v.z + xb.z*w2v.z + xb.w*w3.z;
                    acc1.w += xb.x*w0.w + xb.y*w1v.w + xb.z*w2v.w + xb.w*w3.w;
                }
            }
            *(float4*)&a1s[tg*64 + c]      = acc0;
            *(float4*)&a1s[(tg+16)*64 + c] = acc1;
        }
        __syncthreads();

        // ---- conv2 + ReLU + transposed store. All reads b128.
        {
            const int cq = (tid & 31) * 4;
            const int tg2 = tid >> 5;
            float4 bb = *(const float4*)&b2s[cq];
            float4 acc[4] = {bb, bb, bb, bb};
            #pragma unroll
            for (int i4 = 0; i4 < 16; ++i4) {
                float4 w0 = *(const float4*)&w2s[(i4*4 + 0)*128 + cq];
                float4 wv1 = *(const float4*)&w2s[(i4*4 + 1)*128 + cq];
                float4 wv2 = *(const float4*)&w2s[(i4*4 + 2)*128 + cq];
                float4 w3 = *(const float4*)&w2s[(i4*4 + 3)*128 + cq];
                #pragma unroll
                for (int j = 0; j < 4; ++j) {
                    float4 a = *(const float4*)&a1s[(tg2 + 8*j)*64 + i4*4];
                    acc[j].x += a.x*w0.x + a.y*wv1.x + a.z*wv2.x + a.w*w3.x;
                    acc[j].y += a.x*w0.y + a.y*wv1.y + a.z*wv2.y + a.w*w3.y;
                    acc[j].z += a.x*w0.z + a.y*wv1.z + a.z*wv2.z + a.w*w3.z;
                    acc[j].w += a.x*w0.w + a.y*wv1.w + a.z*wv2.w + a.w*w3.w;
                }
            }
            const long rb = ((long)n*A + 17 + cq)*TPAD;
            #pragma unroll
            for (int j = 0; j < 4; ++j) {
                int t = t0 + tg2 + 8*j;
                if (t < T) {
                    aug_t[rb + 0*TPAD + t] = fmaxf(acc[j].x, 0.f);
                    aug_t[rb + 1*TPAD + t] = fmaxf(acc[j].y, 0.f);
                    aug_t[rb + 2*TPAD + t] = fmaxf(acc[j].z, 0.f);
                    aug_t[rb + 3*TPAD + t] = fmaxf(acc[j].w, 0.f);
                }
            }
        }

        // ---- channels 0..16 (trunc x + time), transposed store
        for (int idx = tid; idx < 17*32; idx += 256) {
            int ch = idx >> 5, tt = idx & 31;
            int t = t0 + tt;
            if (t < T) {
                float val = (ch < 16) ? xs[(l0 + tt + 2)*16 + ch] : (float)t * inv253;
                aug_t[((long)n*A + ch)*TPAD + t] = val;
            }
        }
        __syncthreads();
    }
}

// ---------------------------------------------------------------------------
// Kernel B: depth-2 signature via MFMA bf16-split GEMM.
// s2[i][j] = sum_t m_t[i]*d_t[j]  ==  C = Mbar^T(145xK) . D(Kx145), K=253.
// One block per n, 256 thr = 4 waves (2x2 of 80x80), 5x5 16x16 tiles/wave.
// ---------------------------------------------------------------------------
#define CHT 160
#define LDA2 40

__global__ __launch_bounds__(256) void sig_kernel(
    const float* __restrict__ aug_t,
    unsigned short* __restrict__ sig_hi, unsigned short* __restrict__ sig_lo)
{
    __shared__ __align__(16) unsigned short MhT[CHT*LDA2];
    __shared__ __align__(16) unsigned short MlT[CHT*LDA2];
    __shared__ __align__(16) unsigned short DhT[CHT*LDA2];
    __shared__ __align__(16) unsigned short DlT[CHT*LDA2];

    const int tid = threadIdx.x;
    const int n = blockIdx.x;
    const float* an = aug_t + (long)n*A*TPAD;

    const int lane = tid & 63;
    const int w    = tid >> 6;
    const int wm   = w & 1;
    const int wn   = w >> 1;
    const int frow = lane & 15;
    const int quad = lane >> 4;

    const int ch = tid;   // staging row for tid < CHT
    float a0 = 0.f;
    if (ch < A) a0 = an[ch*TPAD];

    floatx4 acc[5][5];
    #pragma unroll
    for (int i = 0; i < 5; ++i)
        #pragma unroll
        for (int j = 0; j < 5; ++j)
            acc[i][j] = (floatx4){0.f, 0.f, 0.f, 0.f};

    for (int c = 0; c < 8; ++c) {
        const int t0 = c*32;
        if (ch < CHT) {
            unsigned short mh[32], ml[32], dh[32], dl[32];
            if (ch < A) {
                float v[33];
                const float* src = an + ch*TPAD + t0;
                #pragma unroll
                for (int i = 0; i < 8; ++i)
                    *(float4*)&v[i*4] = *(const float4*)(src + i*4);
                v[32] = (t0 + 32 <= 253) ? src[32] : 0.f;
                #pragma unroll
                for (int tl = 0; tl < 32; ++tl) {
                    bool valid = (t0 + tl) <= 252;
                    float x0 = v[tl], x1 = v[tl+1];
                    float d = valid ? (x1 - x0) : 0.f;
                    float m = valid ? (0.5f*(x0 + x1) - a0) : 0.f;
                    unsigned short hb = f2bf(m);
                    mh[tl] = hb; ml[tl] = f2bf(m - bf2f(hb));
                    unsigned short db2 = f2bf(d);
                    dh[tl] = db2; dl[tl] = f2bf(d - bf2f(db2));
                }
            } else {
                #pragma unroll
                for (int tl = 0; tl < 32; ++tl) { mh[tl]=0; ml[tl]=0; dh[tl]=0; dl[tl]=0; }
            }
            #pragma unroll
            for (int p = 0; p < 4; ++p) {
                *(ushort8*)&MhT[ch*LDA2 + p*8] = *(ushort8*)&mh[p*8];
                *(ushort8*)&MlT[ch*LDA2 + p*8] = *(ushort8*)&ml[p*8];
                *(ushort8*)&DhT[ch*LDA2 + p*8] = *(ushort8*)&dh[p*8];
                *(ushort8*)&DlT[ch*LDA2 + p*8] = *(ushort8*)&dl[p*8];
            }
        }
        __syncthreads();

        short8 afh[5], afl[5], bfh[5], bfl[5];
        #pragma unroll
        for (int i = 0; i < 5; ++i) {
            int ar = (wm*80 + i*16 + frow)*LDA2 + quad*8;
            int br = (wn*80 + i*16 + frow)*LDA2 + quad*8;
            afh[i] = *(const short8*)&MhT[ar];
            afl[i] = *(const short8*)&MlT[ar];
            bfh[i] = *(const short8*)&DhT[br];
            bfl[i] = *(const short8*)&DlT[br];
        }
        #pragma unroll
        for (int mt = 0; mt < 5; ++mt)
            #pragma unroll
            for (int nt = 0; nt < 5; ++nt) {
                acc[mt][nt] = __builtin_amdgcn_mfma_f32_16x16x32_bf16(
                    afh[mt], bfh[nt], acc[mt][nt], 0, 0, 0);
                acc[mt][nt] = __builtin_amdgcn_mfma_f32_16x16x32_bf16(
                    afh[mt], bfl[nt], acc[mt][nt], 0, 0, 0);
                acc[mt][nt] = __builtin_amdgcn_mfma_f32_16x16x32_bf16(
                    afl[mt], bfh[nt], acc[mt][nt], 0, 0, 0);
            }
        __syncthreads();
    }

    // epilogue
    unsigned short* sh = sig_hi + (long)n*KP;
    unsigned short* sl = sig_lo + (long)n*KP;
    if (tid < A) {
        float v = an[tid*TPAD + 253] - a0;
        unsigned short hb = f2bf(v);
        sh[tid] = hb;
        sl[tid] = f2bf(v - bf2f(hb));
    }
    if (tid >= 160 && tid < 160 + (KP - SIG_CH)) {
        sh[SIG_CH + tid - 160] = 0;
        sl[SIG_CH + tid - 160] = 0;
    }
    #pragma unroll
    for (int mt = 0; mt < 5; ++mt)
        #pragma unroll
        for (int nt = 0; nt < 5; ++nt) {
            int j = wn*80 + nt*16 + frow;
            int ib = wm*80 + mt*16 + quad*4;
            #pragma unroll
            for (int e = 0; e < 4; ++e) {
                int i = ib + e;
                if (i < A && j < A) {
                    float v = acc[mt][nt][e];
                    unsigned short hb = f2bf(v);
                    sh[A + i*A + j] = hb;
                    sl[A + i*A + j] = f2bf(v - bf2f(hb));
                }
            }
        }
}

// ---------------------------------------------------------------------------
// Kernel W: W[k][o] fp32 -> Wt_hi/Wt_lo[o][KP] bf16 (transposed, split).
// ---------------------------------------------------------------------------
__global__ __launch_bounds__(256) void wconv_kernel(
    const float* __restrict__ W,
    unsigned short* __restrict__ wt_hi, unsigned short* __restrict__ wt_lo)
{
    __shared__ float ls[64][65];
    const int tid = threadIdx.x;
    const int k0 = blockIdx.x * 64;
    const int o0 = blockIdx.y * 64;

    #pragma unroll
    for (int p = 0; p < 16; ++p) {
        int idx = tid + p*256;
        int kk = idx >> 6, oo = idx & 63;
        int k = k0 + kk;
        ls[kk][oo] = (k < SIG_CH) ? W[(long)k*OUT + o0 + oo] : 0.f;
    }
    __syncthreads();

    const int oo = tid >> 2;
    const int kq = (tid & 3) * 16;
    unsigned short hbuf[16], lbuf[16];
    #pragma unroll
    for (int j = 0; j < 16; ++j) {
        float v = ls[kq + j][oo];
        unsigned short hb = f2bf(v);
        hbuf[j] = hb;
        lbuf[j] = f2bf(v - bf2f(hb));
    }
    long off = (long)(o0 + oo)*KP + k0 + kq;
    *(ushort8*)(wt_hi + off)     = *(ushort8*)&hbuf[0];
    *(ushort8*)(wt_hi + off + 8) = *(ushort8*)&hbuf[8];
    *(ushort8*)(wt_lo + off)     = *(ushort8*)&lbuf[0];
    *(ushort8*)(wt_lo + off + 8) = *(ushort8*)&lbuf[8];
}

// ---------------------------------------------------------------------------
// Kernel C: MFMA bf16 split GEMM. part[z] = sig * Wt^T over K-chunk.
// ---------------------------------------------------------------------------
#define SPLITK 61
#define KC 352
#define NSTEP (KC/32)   // 11
#define LDA 40

__global__ __launch_bounds__(256) void gemm_kernel(
    const unsigned short* __restrict__ sig_hi, const unsigned short* __restrict__ sig_lo,
    const unsigned short* __restrict__ wt_hi,  const unsigned short* __restrict__ wt_lo,
    float* __restrict__ part)
{
    __shared__ __align__(16) unsigned short Ah[128*LDA];
    __shared__ __align__(16) unsigned short Al[128*LDA];
    __shared__ __align__(16) unsigned short Bh[128*LDA];
    __shared__ __align__(16) unsigned short Bl[128*LDA];

    const int tid = threadIdx.x;
    const int o0 = blockIdx.x * 128;
    const int n0 = blockIdx.y * 128;
    const int z  = blockIdx.z;
    const int k0 = z * KC;

    const int lane = tid & 63;
    const int w    = tid >> 6;
    const int wm   = w & 1;
    const int wn   = w >> 1;
    const int frow = lane & 15;
    const int quad = lane >> 4;

    const int srow = tid >> 1;
    const int kh   = (tid & 1) * 16;

    const unsigned short* gAh = sig_hi + (long)(n0 + srow)*KP;
    const unsigned short* gAl = sig_lo + (long)(n0 + srow)*KP;
    const unsigned short* gBh = wt_hi  + (long)(o0 + srow)*KP;
    const unsigned short* gBl = wt_lo  + (long)(o0 + srow)*KP;

    ushort8 rah[2], ral[2], rbh[2], rbl[2];
    const ushort8 z8 = {0,0,0,0,0,0,0,0};

    #define GLOAD(s)                                                          \
        {                                                                     \
            int kb = k0 + (s)*32 + kh;                                        \
            if (kb < KP) {                                                    \
                rah[0] = *(const ushort8*)(gAh + kb);                         \
                rah[1] = *(const ushort8*)(gAh + kb + 8);                     \
                ral[0] = *(const ushort8*)(gAl + kb);                         \
                ral[1] = *(const ushort8*)(gAl + kb + 8);                     \
                rbh[0] = *(const ushort8*)(gBh + kb);                         \
                rbh[1] = *(const ushort8*)(gBh + kb + 8);                     \
                rbl[0] = *(const ushort8*)(gBl + kb);                         \
                rbl[1] = *(const ushort8*)(gBl + kb + 8);                     \
            } else {                                                          \
                rah[0]=z8; rah[1]=z8; ral[0]=z8; ral[1]=z8;                   \
                rbh[0]=z8; rbh[1]=z8; rbl[0]=z8; rbl[1]=z8;                   \
            }                                                                 \
        }

    #define LSTORE()                                                          \
        {                                                                     \
            int o = srow*LDA + kh;                                            \
            *(ushort8*)(Ah + o)     = rah[0];                                 \
            *(ushort8*)(Ah + o + 8) = rah[1];                                 \
            *(ushort8*)(Al + o)     = ral[0];                                 \
            *(ushort8*)(Al + o + 8) = ral[1];                                 \
            *(ushort8*)(Bh + o)     = rbh[0];                                 \
            *(ushort8*)(Bh + o + 8) = rbh[1];                                 \
            *(ushort8*)(Bl + o)     = rbl[0];                                 \
            *(ushort8*)(Bl + o + 8) = rbl[1];                                 \
        }

    floatx4 acc[4][4];
    #pragma unroll
    for (int i = 0; i < 4; ++i)
        #pragma unroll
        for (int j = 0; j < 4; ++j)
            acc[i][j] = (floatx4){0.f, 0.f, 0.f, 0.f};

    GLOAD(0);
    LSTORE();
    __syncthreads();

    for (int s = 0; s < NSTEP; ++s) {
        if (s < NSTEP-1) GLOAD(s+1);

        short8 afh[4], afl[4], bfh[4], bfl[4];
        const int aoff = (wm*64 + frow)*LDA + quad*8;
        const int boff = (wn*64 + frow)*LDA + quad*8;
        #pragma unroll
        for (int tI = 0; tI < 4; ++tI) {
            afh[tI] = *(const short8*)(Ah + aoff + tI*16*LDA);
            afl[tI] = *(const short8*)(Al + aoff + tI*16*LDA);
            bfh[tI] = *(const short8*)(Bh + boff + tI*16*LDA);
            bfl[tI] = *(const short8*)(Bl + boff + tI*16*LDA);
        }
        #pragma unroll
        for (int mt = 0; mt < 4; ++mt)
            #pragma unroll
            for (int nt = 0; nt < 4; ++nt) {
                acc[mt][nt] = __builtin_amdgcn_mfma_f32_16x16x32_bf16(
                    afh[mt], bfh[nt], acc[mt][nt], 0, 0, 0);
                acc[mt][nt] = __builtin_amdgcn_mfma_f32_16x16x32_bf16(
                    afh[mt], bfl[nt], acc[mt][nt], 0, 0, 0);
                acc[mt][nt] = __builtin_amdgcn_mfma_f32_16x16x32_bf16(
                    afl[mt], bfh[nt], acc[mt][nt], 0, 0, 0);
            }
        __syncthreads();
        if (s < NSTEP-1) {
            LSTORE();
            __syncthreads();
        }
    }

    float* pz = part + (long)z * (Nn*OUT);
    #pragma unroll
    for (int mt = 0; mt < 4; ++mt)
        #pragma unroll
        for (int nt = 0; nt < 4; ++nt) {
            int col = o0 + wn*64 + nt*16 + frow;
            int rbase = n0 + wm*64 + mt*16 + quad*4;
            #pragma unroll
            for (int e = 0; e < 4; ++e)
                pz[(long)(rbase + e)*OUT + col] = acc[mt][nt][e];
        }
}

// ---------------------------------------------------------------------------
// Kernel D: out[n][o] = lin_b[o] + sum_z part[z][n][o]
// ---------------------------------------------------------------------------
__global__ __launch_bounds__(256) void reduce_kernel(
    const float* __restrict__ part, const float* __restrict__ lb,
    float* __restrict__ out)
{
    int idx = blockIdx.x * 256 + threadIdx.x;
    float s = lb[idx & 255];
    #pragma unroll 8
    for (int z = 0; z < SPLITK; ++z)
        s += part[(long)z * (Nn*OUT) + idx];
    out[idx] = s;
}

// ---------------------------------------------------------------------------
extern "C" void kernel_launch(void* const* d_in, const int* in_sizes, int n_in,
                              void* d_out, int out_size, void* d_ws, size_t ws_size,
                              hipStream_t stream) {
    const float* q  = (const float*)d_in[0];
    const float* w1 = (const float*)d_in[4];
    const float* b1 = (const float*)d_in[5];
    const float* w2 = (const float*)d_in[6];
    const float* b2 = (const float*)d_in[7];
    const float* lw = (const float*)d_in[8];
    const float* lb = (const float*)d_in[9];
    float* out = (float*)d_out;

    // ws layout (peak 59.71 MB):
    //   [0]          sig_hi  (256*KP*2 = 10,846,208)
    //   [10846208]   sig_lo  (10,846,208)
    //   [21692416]   aug_t fp32 [256][145][256] (38,010,880) -- dead after sig:
    //     [21692416] wt_hi (10,846,208)
    //     [32538624] wt_lo (10,846,208)
    //     [43384832] part  (61*65536*4 = 15,990,784)  (ends 59,375,616)
    char* ws = (char*)d_ws;
    unsigned short* sig_hi = (unsigned short*)ws;
    unsigned short* sig_lo = (unsigned short*)(ws + 10846208);
    float*          aug_t  = (float*)(ws + 21692416);
    unsigned short* wt_hi  = (unsigned short*)(ws + 21692416);
    unsigned short* wt_lo  = (unsigned short*)(ws + 32538624);
    float*          part   = (float*)(ws + 43384832);

    aug_kernel<<<dim3(4, Nn), 256, 0, stream>>>(q, w1, b1, w2, b2, aug_t);
    sig_kernel<<<Nn, 256, 0, stream>>>(aug_t, sig_hi, sig_lo);
    wconv_kernel<<<dim3(KP/64, OUT/64), 256, 0, stream>>>(lw, wt_hi, wt_lo);
    gemm_kernel<<<dim3(2, 2, SPLITK), 256, 0, stream>>>(sig_hi, sig_lo, wt_hi, wt_lo, part);
    reduce_kernel<<<(Nn*OUT)/256, 256, 0, stream>>>(part, lb, out);
}

// Round 8
// 204.875 us; speedup vs baseline: 1.2054x; 1.2054x over previous
//
#include <hip/hip_runtime.h>
#include <hip/hip_bf16.h>

// Problem constants
#define Bq 32
#define Lq 256
#define Hq 8
#define Eq 16
#define Nn (Bq*Hq)        // 256 sequences
#define T 254             // Lq - 3 + 1
#define A 145             // E + 1 + 128 augmented channels
#define SIG_CH (A + A*A)  // 21170
#define KP 21184          // padded K (mult of 32), bf16 arrays
#define OUT 256
#define TPAD 256          // aug_t row stride (t dimension)

typedef __attribute__((ext_vector_type(8))) short short8;
typedef __attribute__((ext_vector_type(8))) unsigned short ushort8;
typedef __attribute__((ext_vector_type(4))) float floatx4;

static __device__ __forceinline__ unsigned short f2bf(float v) {
    unsigned int u = __float_as_uint(v);
    unsigned int r = (u + 0x7FFFu + ((u >> 16) & 1u)) >> 16;
    return (unsigned short)r;
}
static __device__ __forceinline__ float bf2f(unsigned short b) {
    return __uint_as_float(((unsigned int)b) << 16);
}

// ---------------------------------------------------------------------------
// Kernel A: conv1(k=3,16->64) -> conv2(k=1,64->128)+ReLU.
// Output TRANSPOSED: aug_t[n][ch][t], t contiguous (TPAD=256).
// grid (4, 256), 256 threads.
// R8: R6-proven conv loops (VGPR 92); w2 read from GLOBAL (coalesced,
// L2-resident) -> LDS/block 58KB -> 25.6KB -> ~5 blocks/CU.
// ---------------------------------------------------------------------------
__global__ __launch_bounds__(256) void aug_kernel(
    const float* __restrict__ q,
    const float* __restrict__ w1, const float* __restrict__ b1,
    const float* __restrict__ w2, const float* __restrict__ b2,
    float* __restrict__ aug_t)
{
    __shared__ __align__(16) float w1s[48*64];    // 12KB
    __shared__ __align__(16) float b1s[64];
    __shared__ __align__(16) float b2s[128];
    __shared__ __align__(16) float xs[68*16];     // 4.35KB
    __shared__ __align__(16) float a1s[32*64];    // 8KB

    const int tid = threadIdx.x;
    const int n = blockIdx.y;
    const int b = n >> 3, h = n & 7;
    const int tb0 = blockIdx.x * 64;

    for (int i = tid; i < 48*64; i += 256) w1s[i] = w1[i];
    if (tid < 64)  b1s[tid] = b1[tid];
    if (tid < 128) b2s[tid] = b2[tid];
    {
        const float4* q4 = (const float4*)q + ((long)(b*Lq)*Hq + h)*4;
        float4* xs4 = (float4*)xs;
        for (int i = tid; i < 68*4; i += 256) {
            int rr = i >> 2, e4 = i & 3;
            int t = tb0 + rr; if (t > 255) t = 255;
            xs4[rr*4 + e4] = q4[t*32 + e4];
        }
    }
    __syncthreads();

    const float inv253 = 1.0f / 253.0f;
    const float4* w2g = (const float4*)w2;   // [i][c/4], c quads

    #pragma unroll
    for (int sub = 0; sub < 2; ++sub) {
        const int t0 = tb0 + sub*32;
        const int l0 = sub*32;
        // ---- conv1 (R6 form: scalar x reads, b128 w reads)
        {
            const int c = (tid & 15) * 4;
            const int tg = tid >> 4;
            float4 bb = *(const float4*)&b1s[c];
            float4 acc0 = bb, acc1 = bb;
            #pragma unroll
            for (int j = 0; j < 48; ++j) {
                const int dt = j >> 4, i = j & 15;
                float4 w = *(const float4*)&w1s[j*64 + c];
                float xa = xs[(l0 + tg + dt)*16 + i];
                float xb = xs[(l0 + tg + 16 + dt)*16 + i];
                acc0.x += xa*w.x; acc0.y += xa*w.y; acc0.z += xa*w.z; acc0.w += xa*w.w;
                acc1.x += xb*w.x; acc1.y += xb*w.y; acc1.z += xb*w.z; acc1.w += xb*w.w;
            }
            *(float4*)&a1s[tg*64 + c]      = acc0;
            *(float4*)&a1s[(tg+16)*64 + c] = acc1;
        }
        __syncthreads();

        // ---- conv2 + ReLU + transposed store. w2 from global (coalesced).
        {
            const int cqi = tid & 31;          // c quad index
            const int tg2 = tid >> 5;
            float4 bb = *(const float4*)&b2s[cqi*4];
            float4 acc[4] = {bb, bb, bb, bb};
            #pragma unroll 4
            for (int i = 0; i < 64; ++i) {
                float4 w = w2g[i*32 + cqi];
                #pragma unroll
                for (int j = 0; j < 4; ++j) {
                    float a = a1s[(tg2 + 8*j)*64 + i];
                    acc[j].x += a*w.x; acc[j].y += a*w.y; acc[j].z += a*w.z; acc[j].w += a*w.w;
                }
            }
            const long rb = ((long)n*A + 17 + cqi*4)*TPAD;
            #pragma unroll
            for (int j = 0; j < 4; ++j) {
                int t = t0 + tg2 + 8*j;
                if (t < T) {
                    aug_t[rb + 0*TPAD + t] = fmaxf(acc[j].x, 0.f);
                    aug_t[rb + 1*TPAD + t] = fmaxf(acc[j].y, 0.f);
                    aug_t[rb + 2*TPAD + t] = fmaxf(acc[j].z, 0.f);
                    aug_t[rb + 3*TPAD + t] = fmaxf(acc[j].w, 0.f);
                }
            }
        }

        // ---- channels 0..16 (trunc x + time), transposed store
        for (int idx = tid; idx < 17*32; idx += 256) {
            int ch = idx >> 5, tt = idx & 31;
            int t = t0 + tt;
            if (t < T) {
                float val = (ch < 16) ? xs[(l0 + tt + 2)*16 + ch] : (float)t * inv253;
                aug_t[((long)n*A + ch)*TPAD + t] = val;
            }
        }
        __syncthreads();
    }
}

// ---------------------------------------------------------------------------
// Kernel B: depth-2 signature via MFMA bf16-split GEMM.
// s2[i][j] = sum_t m_t[i]*d_t[j]  ==  C = Mbar^T(145xK) . D(Kx145), K=253.
// One block per n, 256 thr = 4 waves (2x2 of 80x80), 5x5 16x16 tiles/wave.
// ---------------------------------------------------------------------------
#define CHT 160
#define LDA2 40

__global__ __launch_bounds__(256) void sig_kernel(
    const float* __restrict__ aug_t,
    unsigned short* __restrict__ sig_hi, unsigned short* __restrict__ sig_lo)
{
    __shared__ __align__(16) unsigned short MhT[CHT*LDA2];
    __shared__ __align__(16) unsigned short MlT[CHT*LDA2];
    __shared__ __align__(16) unsigned short DhT[CHT*LDA2];
    __shared__ __align__(16) unsigned short DlT[CHT*LDA2];

    const int tid = threadIdx.x;
    const int n = blockIdx.x;
    const float* an = aug_t + (long)n*A*TPAD;

    const int lane = tid & 63;
    const int w    = tid >> 6;
    const int wm   = w & 1;
    const int wn   = w >> 1;
    const int frow = lane & 15;
    const int quad = lane >> 4;

    const int ch = tid;   // staging row for tid < CHT
    float a0 = 0.f;
    if (ch < A) a0 = an[ch*TPAD];

    floatx4 acc[5][5];
    #pragma unroll
    for (int i = 0; i < 5; ++i)
        #pragma unroll
        for (int j = 0; j < 5; ++j)
            acc[i][j] = (floatx4){0.f, 0.f, 0.f, 0.f};

    for (int c = 0; c < 8; ++c) {
        const int t0 = c*32;
        if (ch < CHT) {
            unsigned short mh[32], ml[32], dh[32], dl[32];
            if (ch < A) {
                float v[33];
                const float* src = an + ch*TPAD + t0;
                #pragma unroll
                for (int i = 0; i < 8; ++i)
                    *(float4*)&v[i*4] = *(const float4*)(src + i*4);
                v[32] = (t0 + 32 <= 253) ? src[32] : 0.f;
                #pragma unroll
                for (int tl = 0; tl < 32; ++tl) {
                    bool valid = (t0 + tl) <= 252;
                    float x0 = v[tl], x1 = v[tl+1];
                    float d = valid ? (x1 - x0) : 0.f;
                    float m = valid ? (0.5f*(x0 + x1) - a0) : 0.f;
                    unsigned short hb = f2bf(m);
                    mh[tl] = hb; ml[tl] = f2bf(m - bf2f(hb));
                    unsigned short db2 = f2bf(d);
                    dh[tl] = db2; dl[tl] = f2bf(d - bf2f(db2));
                }
            } else {
                #pragma unroll
                for (int tl = 0; tl < 32; ++tl) { mh[tl]=0; ml[tl]=0; dh[tl]=0; dl[tl]=0; }
            }
            #pragma unroll
            for (int p = 0; p < 4; ++p) {
                *(ushort8*)&MhT[ch*LDA2 + p*8] = *(ushort8*)&mh[p*8];
                *(ushort8*)&MlT[ch*LDA2 + p*8] = *(ushort8*)&ml[p*8];
                *(ushort8*)&DhT[ch*LDA2 + p*8] = *(ushort8*)&dh[p*8];
                *(ushort8*)&DlT[ch*LDA2 + p*8] = *(ushort8*)&dl[p*8];
            }
        }
        __syncthreads();

        short8 afh[5], afl[5], bfh[5], bfl[5];
        #pragma unroll
        for (int i = 0; i < 5; ++i) {
            int ar = (wm*80 + i*16 + frow)*LDA2 + quad*8;
            int br = (wn*80 + i*16 + frow)*LDA2 + quad*8;
            afh[i] = *(const short8*)&MhT[ar];
            afl[i] = *(const short8*)&MlT[ar];
            bfh[i] = *(const short8*)&DhT[br];
            bfl[i] = *(const short8*)&DlT[br];
        }
        #pragma unroll
        for (int mt = 0; mt < 5; ++mt)
            #pragma unroll
            for (int nt = 0; nt < 5; ++nt) {
                acc[mt][nt] = __builtin_amdgcn_mfma_f32_16x16x32_bf16(
                    afh[mt], bfh[nt], acc[mt][nt], 0, 0, 0);
                acc[mt][nt] = __builtin_amdgcn_mfma_f32_16x16x32_bf16(
                    afh[mt], bfl[nt], acc[mt][nt], 0, 0, 0);
                acc[mt][nt] = __builtin_amdgcn_mfma_f32_16x16x32_bf16(
                    afl[mt], bfh[nt], acc[mt][nt], 0, 0, 0);
            }
        __syncthreads();
    }

    // epilogue
    unsigned short* sh = sig_hi + (long)n*KP;
    unsigned short* sl = sig_lo + (long)n*KP;
    if (tid < A) {
        float v = an[tid*TPAD + 253] - a0;
        unsigned short hb = f2bf(v);
        sh[tid] = hb;
        sl[tid] = f2bf(v - bf2f(hb));
    }
    if (tid >= 160 && tid < 160 + (KP - SIG_CH)) {
        sh[SIG_CH + tid - 160] = 0;
        sl[SIG_CH + tid - 160] = 0;
    }
    #pragma unroll
    for (int mt = 0; mt < 5; ++mt)
        #pragma unroll
        for (int nt = 0; nt < 5; ++nt) {
            int j = wn*80 + nt*16 + frow;
            int ib = wm*80 + mt*16 + quad*4;
            #pragma unroll
            for (int e = 0; e < 4; ++e) {
                int i = ib + e;
                if (i < A && j < A) {
                    float v = acc[mt][nt][e];
                    unsigned short hb = f2bf(v);
                    sh[A + i*A + j] = hb;
                    sl[A + i*A + j] = f2bf(v - bf2f(hb));
                }
            }
        }
}

// ---------------------------------------------------------------------------
// Kernel W: W[k][o] fp32 -> Wt_hi/Wt_lo[o][KP] bf16 (transposed, split).
// ---------------------------------------------------------------------------
__global__ __launch_bounds__(256) void wconv_kernel(
    const float* __restrict__ W,
    unsigned short* __restrict__ wt_hi, unsigned short* __restrict__ wt_lo)
{
    __shared__ float ls[64][65];
    const int tid = threadIdx.x;
    const int k0 = blockIdx.x * 64;
    const int o0 = blockIdx.y * 64;

    #pragma unroll
    for (int p = 0; p < 16; ++p) {
        int idx = tid + p*256;
        int kk = idx >> 6, oo = idx & 63;
        int k = k0 + kk;
        ls[kk][oo] = (k < SIG_CH) ? W[(long)k*OUT + o0 + oo] : 0.f;
    }
    __syncthreads();

    const int oo = tid >> 2;
    const int kq = (tid & 3) * 16;
    unsigned short hbuf[16], lbuf[16];
    #pragma unroll
    for (int j = 0; j < 16; ++j) {
        float v = ls[kq + j][oo];
        unsigned short hb = f2bf(v);
        hbuf[j] = hb;
        lbuf[j] = f2bf(v - bf2f(hb));
    }
    long off = (long)(o0 + oo)*KP + k0 + kq;
    *(ushort8*)(wt_hi + off)     = *(ushort8*)&hbuf[0];
    *(ushort8*)(wt_hi + off + 8) = *(ushort8*)&hbuf[8];
    *(ushort8*)(wt_lo + off)     = *(ushort8*)&lbuf[0];
    *(ushort8*)(wt_lo + off + 8) = *(ushort8*)&lbuf[8];
}

// ---------------------------------------------------------------------------
// Kernel C: MFMA bf16 split GEMM. part[z] = sig * Wt^T over K-chunk.
// ---------------------------------------------------------------------------
#define SPLITK 61
#define KC 352
#define NSTEP (KC/32)   // 11
#define LDA 40

__global__ __launch_bounds__(256) void gemm_kernel(
    const unsigned short* __restrict__ sig_hi, const unsigned short* __restrict__ sig_lo,
    const unsigned short* __restrict__ wt_hi,  const unsigned short* __restrict__ wt_lo,
    float* __restrict__ part)
{
    __shared__ __align__(16) unsigned short Ah[128*LDA];
    __shared__ __align__(16) unsigned short Al[128*LDA];
    __shared__ __align__(16) unsigned short Bh[128*LDA];
    __shared__ __align__(16) unsigned short Bl[128*LDA];

    const int tid = threadIdx.x;
    const int o0 = blockIdx.x * 128;
    const int n0 = blockIdx.y * 128;
    const int z  = blockIdx.z;
    const int k0 = z * KC;

    const int lane = tid & 63;
    const int w    = tid >> 6;
    const int wm   = w & 1;
    const int wn   = w >> 1;
    const int frow = lane & 15;
    const int quad = lane >> 4;

    const int srow = tid >> 1;
    const int kh   = (tid & 1) * 16;

    const unsigned short* gAh = sig_hi + (long)(n0 + srow)*KP;
    const unsigned short* gAl = sig_lo + (long)(n0 + srow)*KP;
    const unsigned short* gBh = wt_hi  + (long)(o0 + srow)*KP;
    const unsigned short* gBl = wt_lo  + (long)(o0 + srow)*KP;

    ushort8 rah[2], ral[2], rbh[2], rbl[2];
    const ushort8 z8 = {0,0,0,0,0,0,0,0};

    #define GLOAD(s)                                                          \
        {                                                                     \
            int kb = k0 + (s)*32 + kh;                                        \
            if (kb < KP) {                                                    \
                rah[0] = *(const ushort8*)(gAh + kb);                         \
                rah[1] = *(const ushort8*)(gAh + kb + 8);                     \
                ral[0] = *(const ushort8*)(gAl + kb);                         \
                ral[1] = *(const ushort8*)(gAl + kb + 8);                     \
                rbh[0] = *(const ushort8*)(gBh + kb);                         \
                rbh[1] = *(const ushort8*)(gBh + kb + 8);                     \
                rbl[0] = *(const ushort8*)(gBl + kb);                         \
                rbl[1] = *(const ushort8*)(gBl + kb + 8);                     \
            } else {                                                          \
                rah[0]=z8; rah[1]=z8; ral[0]=z8; ral[1]=z8;                   \
                rbh[0]=z8; rbh[1]=z8; rbl[0]=z8; rbl[1]=z8;                   \
            }                                                                 \
        }

    #define LSTORE()                                                          \
        {                                                                     \
            int o = srow*LDA + kh;                                            \
            *(ushort8*)(Ah + o)     = rah[0];                                 \
            *(ushort8*)(Ah + o + 8) = rah[1];                                 \
            *(ushort8*)(Al + o)     = ral[0];                                 \
            *(ushort8*)(Al + o + 8) = ral[1];                                 \
            *(ushort8*)(Bh + o)     = rbh[0];                                 \
            *(ushort8*)(Bh + o + 8) = rbh[1];                                 \
            *(ushort8*)(Bl + o)     = rbl[0];                                 \
            *(ushort8*)(Bl + o + 8) = rbl[1];                                 \
        }

    floatx4 acc[4][4];
    #pragma unroll
    for (int i = 0; i < 4; ++i)
        #pragma unroll
        for (int j = 0; j < 4; ++j)
            acc[i][j] = (floatx4){0.f, 0.f, 0.f, 0.f};

    GLOAD(0);
    LSTORE();
    __syncthreads();

    for (int s = 0; s < NSTEP; ++s) {
        if (s < NSTEP-1) GLOAD(s+1);

        short8 afh[4], afl[4], bfh[4], bfl[4];
        const int aoff = (wm*64 + frow)*LDA + quad*8;
        const int boff = (wn*64 + frow)*LDA + quad*8;
        #pragma unroll
        for (int tI = 0; tI < 4; ++tI) {
            afh[tI] = *(const short8*)(Ah + aoff + tI*16*LDA);
            afl[tI] = *(const short8*)(Al + aoff + tI*16*LDA);
            bfh[tI] = *(const short8*)(Bh + boff + tI*16*LDA);
            bfl[tI] = *(const short8*)(Bl + boff + tI*16*LDA);
        }
        #pragma unroll
        for (int mt = 0; mt < 4; ++mt)
            #pragma unroll
            for (int nt = 0; nt < 4; ++nt) {
                acc[mt][nt] = __builtin_amdgcn_mfma_f32_16x16x32_bf16(
                    afh[mt], bfh[nt], acc[mt][nt], 0, 0, 0);
                acc[mt][nt] = __builtin_amdgcn_mfma_f32_16x16x32_bf16(
                    afh[mt], bfl[nt], acc[mt][nt], 0, 0, 0);
                acc[mt][nt] = __builtin_amdgcn_mfma_f32_16x16x32_bf16(
                    afl[mt], bfh[nt], acc[mt][nt], 0, 0, 0);
            }
        __syncthreads();
        if (s < NSTEP-1) {
            LSTORE();
            __syncthreads();
        }
    }

    float* pz = part + (long)z * (Nn*OUT);
    #pragma unroll
    for (int mt = 0; mt < 4; ++mt)
        #pragma unroll
        for (int nt = 0; nt < 4; ++nt) {
            int col = o0 + wn*64 + nt*16 + frow;
            int rbase = n0 + wm*64 + mt*16 + quad*4;
            #pragma unroll
            for (int e = 0; e < 4; ++e)
                pz[(long)(rbase + e)*OUT + col] = acc[mt][nt][e];
        }
}

// ---------------------------------------------------------------------------
// Kernel D: out[n][o] = lin_b[o] + sum_z part[z][n][o]
// ---------------------------------------------------------------------------
__global__ __launch_bounds__(256) void reduce_kernel(
    const float* __restrict__ part, const float* __restrict__ lb,
    float* __restrict__ out)
{
    int idx = blockIdx.x * 256 + threadIdx.x;
    float s = lb[idx & 255];
    #pragma unroll 8
    for (int z = 0; z < SPLITK; ++z)
        s += part[(long)z * (Nn*OUT) + idx];
    out[idx] = s;
}

// ---------------------------------------------------------------------------
extern "C" void kernel_launch(void* const* d_in, const int* in_sizes, int n_in,
                              void* d_out, int out_size, void* d_ws, size_t ws_size,
                              hipStream_t stream) {
    const float* q  = (const float*)d_in[0];
    const float* w1 = (const float*)d_in[4];
    const float* b1 = (const float*)d_in[5];
    const float* w2 = (const float*)d_in[6];
    const float* b2 = (const float*)d_in[7];
    const float* lw = (const float*)d_in[8];
    const float* lb = (const float*)d_in[9];
    float* out = (float*)d_out;

    // ws layout (peak 59.71 MB):
    //   [0]          sig_hi  (256*KP*2 = 10,846,208)
    //   [10846208]   sig_lo  (10,846,208)
    //   [21692416]   aug_t fp32 [256][145][256] (38,010,880) -- dead after sig:
    //     [21692416] wt_hi (10,846,208)
    //     [32538624] wt_lo (10,846,208)
    //     [43384832] part  (61*65536*4 = 15,990,784)  (ends 59,375,616)
    char* ws = (char*)d_ws;
    unsigned short* sig_hi = (unsigned short*)ws;
    unsigned short* sig_lo = (unsigned short*)(ws + 10846208);
    float*          aug_t  = (float*)(ws + 21692416);
    unsigned short* wt_hi  = (unsigned short*)(ws + 21692416);
    unsigned short* wt_lo  = (unsigned short*)(ws + 32538624);
    float*          part   = (float*)(ws + 43384832);

    aug_kernel<<<dim3(4, Nn), 256, 0, stream>>>(q, w1, b1, w2, b2, aug_t);
    sig_kernel<<<Nn, 256, 0, stream>>>(aug_t, sig_hi, sig_lo);
    wconv_kernel<<<dim3(KP/64, OUT/64), 256, 0, stream>>>(lw, wt_hi, wt_lo);
    gemm_kernel<<<dim3(2, 2, SPLITK), 256, 0, stream>>>(sig_hi, sig_lo, wt_hi, wt_lo, part);
    reduce_kernel<<<(Nn*OUT)/256, 256, 0, stream>>>(part, lb, out);
}

// Round 9
// 196.991 us; speedup vs baseline: 1.2537x; 1.0400x over previous
//
#include <hip/hip_runtime.h>
#include <hip/hip_bf16.h>

// Problem constants
#define Bq 32
#define Lq 256
#define Hq 8
#define Eq 16
#define Nn (Bq*Hq)        // 256 sequences
#define T 254             // Lq - 3 + 1
#define A 145             // E + 1 + 128 augmented channels
#define SIG_CH (A + A*A)  // 21170
#define KP 21184          // padded K (mult of 32), bf16 arrays
#define OUT 256
#define TPAD 256          // aug_t row stride (t dimension)
#define OTS 35            // outtile LDS row stride (floats)

typedef __attribute__((ext_vector_type(8))) short short8;
typedef __attribute__((ext_vector_type(8))) unsigned short ushort8;
typedef __attribute__((ext_vector_type(4))) float floatx4;

static __device__ __forceinline__ unsigned short f2bf(float v) {
    unsigned int u = __float_as_uint(v);
    unsigned int r = (u + 0x7FFFu + ((u >> 16) & 1u)) >> 16;
    return (unsigned short)r;
}
static __device__ __forceinline__ float bf2f(unsigned short b) {
    return __uint_as_float(((unsigned int)b) << 16);
}

// ---------------------------------------------------------------------------
// Kernel A: conv1(k=3,16->64) -> conv2(k=1,64->128)+ReLU.
// Output TRANSPOSED: aug_t[n][ch][t], t contiguous (TPAD=256).
// grid (4, 256), 256 threads.
// R9: outputs staged in LDS outtile, flushed with t-contiguous COALESCED
// stores (2 cache lines per wave-instr instead of 64). w2 read from global
// (coalesced/broadcast, L2-resident).
// ---------------------------------------------------------------------------
__global__ __launch_bounds__(256) void aug_kernel(
    const float* __restrict__ q,
    const float* __restrict__ w1, const float* __restrict__ b1,
    const float* __restrict__ w2, const float* __restrict__ b2,
    float* __restrict__ aug_t)
{
    __shared__ __align__(16) float w1s[48*64];    // 12KB
    __shared__ __align__(16) float b1s[64];
    __shared__ __align__(16) float b2s[128];
    __shared__ __align__(16) float xs[68*16];     // 4.35KB
    __shared__ __align__(16) float a1s[32*64];    // 8KB
    __shared__ __align__(16) float outs[A*OTS];   // 20.3KB output tile [ch][t]

    const int tid = threadIdx.x;
    const int n = blockIdx.y;
    const int b = n >> 3, h = n & 7;
    const int tb0 = blockIdx.x * 64;

    for (int i = tid; i < 48*64; i += 256) w1s[i] = w1[i];
    if (tid < 64)  b1s[tid] = b1[tid];
    if (tid < 128) b2s[tid] = b2[tid];
    {
        const float4* q4 = (const float4*)q + ((long)(b*Lq)*Hq + h)*4;
        float4* xs4 = (float4*)xs;
        for (int i = tid; i < 68*4; i += 256) {
            int rr = i >> 2, e4 = i & 3;
            int t = tb0 + rr; if (t > 255) t = 255;
            xs4[rr*4 + e4] = q4[t*32 + e4];
        }
    }
    __syncthreads();

    const float inv253 = 1.0f / 253.0f;
    const float4* w2g = (const float4*)w2;   // [i][c/4]

    #pragma unroll
    for (int sub = 0; sub < 2; ++sub) {
        const int t0 = tb0 + sub*32;
        const int l0 = sub*32;
        // ---- conv1 (R6/R8-proven form: scalar x reads, b128 w reads)
        {
            const int c = (tid & 15) * 4;
            const int tg = tid >> 4;
            float4 bb = *(const float4*)&b1s[c];
            float4 acc0 = bb, acc1 = bb;
            #pragma unroll
            for (int j = 0; j < 48; ++j) {
                const int dt = j >> 4, i = j & 15;
                float4 w = *(const float4*)&w1s[j*64 + c];
                float xa = xs[(l0 + tg + dt)*16 + i];
                float xb = xs[(l0 + tg + 16 + dt)*16 + i];
                acc0.x += xa*w.x; acc0.y += xa*w.y; acc0.z += xa*w.z; acc0.w += xa*w.w;
                acc1.x += xb*w.x; acc1.y += xb*w.y; acc1.z += xb*w.z; acc1.w += xb*w.w;
            }
            *(float4*)&a1s[tg*64 + c]      = acc0;
            *(float4*)&a1s[(tg+16)*64 + c] = acc1;
        }
        __syncthreads();

        // ---- conv2 + ReLU -> LDS outtile. w2 from global (coalesced).
        {
            const int cqi = tid & 31;          // c quad index
            const int tg2 = tid >> 5;
            float4 bb = *(const float4*)&b2s[cqi*4];
            float4 acc[4] = {bb, bb, bb, bb};
            #pragma unroll 4
            for (int i = 0; i < 64; ++i) {
                float4 w = w2g[i*32 + cqi];
                #pragma unroll
                for (int j = 0; j < 4; ++j) {
                    float a = a1s[(tg2 + 8*j)*64 + i];
                    acc[j].x += a*w.x; acc[j].y += a*w.y; acc[j].z += a*w.z; acc[j].w += a*w.w;
                }
            }
            #pragma unroll
            for (int j = 0; j < 4; ++j) {
                int tl = tg2 + 8*j;
                float* o = &outs[(17 + cqi*4)*OTS + tl];
                o[0*OTS] = fmaxf(acc[j].x, 0.f);
                o[1*OTS] = fmaxf(acc[j].y, 0.f);
                o[2*OTS] = fmaxf(acc[j].z, 0.f);
                o[3*OTS] = fmaxf(acc[j].w, 0.f);
            }
        }

        // ---- channels 0..16 (trunc x + time) -> LDS outtile
        for (int idx = tid; idx < 17*32; idx += 256) {
            int ch = idx >> 5, tt = idx & 31;
            int t = t0 + tt;
            float val = (ch < 16) ? xs[(l0 + tt + 2)*16 + ch] : (float)t * inv253;
            outs[ch*OTS + tt] = val;
        }
        __syncthreads();

        // ---- coalesced flush: 2 full 128B rows per wave-instr
        // (values at t>=T are garbage but masked downstream in sig_kernel)
        {
            const long nb = (long)n*A;
            for (int idx = tid; idx < A*32; idx += 256) {
                int row = idx >> 5, tt = idx & 31;
                aug_t[(nb + row)*TPAD + t0 + tt] = outs[row*OTS + tt];
            }
        }
        __syncthreads();
    }
}

// ---------------------------------------------------------------------------
// Kernel B: depth-2 signature via MFMA bf16-split GEMM.
// s2[i][j] = sum_t m_t[i]*d_t[j]  ==  C = Mbar^T(145xK) . D(Kx145), K=253.
// One block per n, 256 thr = 4 waves (2x2 of 80x80), 5x5 16x16 tiles/wave.
// ---------------------------------------------------------------------------
#define CHT 160
#define LDA2 40

__global__ __launch_bounds__(256) void sig_kernel(
    const float* __restrict__ aug_t,
    unsigned short* __restrict__ sig_hi, unsigned short* __restrict__ sig_lo)
{
    __shared__ __align__(16) unsigned short MhT[CHT*LDA2];
    __shared__ __align__(16) unsigned short MlT[CHT*LDA2];
    __shared__ __align__(16) unsigned short DhT[CHT*LDA2];
    __shared__ __align__(16) unsigned short DlT[CHT*LDA2];

    const int tid = threadIdx.x;
    const int n = blockIdx.x;
    const float* an = aug_t + (long)n*A*TPAD;

    const int lane = tid & 63;
    const int w    = tid >> 6;
    const int wm   = w & 1;
    const int wn   = w >> 1;
    const int frow = lane & 15;
    const int quad = lane >> 4;

    const int ch = tid;   // staging row for tid < CHT
    float a0 = 0.f;
    if (ch < A) a0 = an[ch*TPAD];

    floatx4 acc[5][5];
    #pragma unroll
    for (int i = 0; i < 5; ++i)
        #pragma unroll
        for (int j = 0; j < 5; ++j)
            acc[i][j] = (floatx4){0.f, 0.f, 0.f, 0.f};

    for (int c = 0; c < 8; ++c) {
        const int t0 = c*32;
        if (ch < CHT) {
            unsigned short mh[32], ml[32], dh[32], dl[32];
            if (ch < A) {
                float v[33];
                const float* src = an + ch*TPAD + t0;
                #pragma unroll
                for (int i = 0; i < 8; ++i)
                    *(float4*)&v[i*4] = *(const float4*)(src + i*4);
                v[32] = (t0 + 32 <= 253) ? src[32] : 0.f;
                #pragma unroll
                for (int tl = 0; tl < 32; ++tl) {
                    bool valid = (t0 + tl) <= 252;
                    float x0 = v[tl], x1 = v[tl+1];
                    float d = valid ? (x1 - x0) : 0.f;
                    float m = valid ? (0.5f*(x0 + x1) - a0) : 0.f;
                    unsigned short hb = f2bf(m);
                    mh[tl] = hb; ml[tl] = f2bf(m - bf2f(hb));
                    unsigned short db2 = f2bf(d);
                    dh[tl] = db2; dl[tl] = f2bf(d - bf2f(db2));
                }
            } else {
                #pragma unroll
                for (int tl = 0; tl < 32; ++tl) { mh[tl]=0; ml[tl]=0; dh[tl]=0; dl[tl]=0; }
            }
            #pragma unroll
            for (int p = 0; p < 4; ++p) {
                *(ushort8*)&MhT[ch*LDA2 + p*8] = *(ushort8*)&mh[p*8];
                *(ushort8*)&MlT[ch*LDA2 + p*8] = *(ushort8*)&ml[p*8];
                *(ushort8*)&DhT[ch*LDA2 + p*8] = *(ushort8*)&dh[p*8];
                *(ushort8*)&DlT[ch*LDA2 + p*8] = *(ushort8*)&dl[p*8];
            }
        }
        __syncthreads();

        short8 afh[5], afl[5], bfh[5], bfl[5];
        #pragma unroll
        for (int i = 0; i < 5; ++i) {
            int ar = (wm*80 + i*16 + frow)*LDA2 + quad*8;
            int br = (wn*80 + i*16 + frow)*LDA2 + quad*8;
            afh[i] = *(const short8*)&MhT[ar];
            afl[i] = *(const short8*)&MlT[ar];
            bfh[i] = *(const short8*)&DhT[br];
            bfl[i] = *(const short8*)&DlT[br];
        }
        #pragma unroll
        for (int mt = 0; mt < 5; ++mt)
            #pragma unroll
            for (int nt = 0; nt < 5; ++nt) {
                acc[mt][nt] = __builtin_amdgcn_mfma_f32_16x16x32_bf16(
                    afh[mt], bfh[nt], acc[mt][nt], 0, 0, 0);
                acc[mt][nt] = __builtin_amdgcn_mfma_f32_16x16x32_bf16(
                    afh[mt], bfl[nt], acc[mt][nt], 0, 0, 0);
                acc[mt][nt] = __builtin_amdgcn_mfma_f32_16x16x32_bf16(
                    afl[mt], bfh[nt], acc[mt][nt], 0, 0, 0);
            }
        __syncthreads();
    }

    // epilogue
    unsigned short* sh = sig_hi + (long)n*KP;
    unsigned short* sl = sig_lo + (long)n*KP;
    if (tid < A) {
        float v = an[tid*TPAD + 253] - a0;
        unsigned short hb = f2bf(v);
        sh[tid] = hb;
        sl[tid] = f2bf(v - bf2f(hb));
    }
    if (tid >= 160 && tid < 160 + (KP - SIG_CH)) {
        sh[SIG_CH + tid - 160] = 0;
        sl[SIG_CH + tid - 160] = 0;
    }
    #pragma unroll
    for (int mt = 0; mt < 5; ++mt)
        #pragma unroll
        for (int nt = 0; nt < 5; ++nt) {
            int j = wn*80 + nt*16 + frow;
            int ib = wm*80 + mt*16 + quad*4;
            #pragma unroll
            for (int e = 0; e < 4; ++e) {
                int i = ib + e;
                if (i < A && j < A) {
                    float v = acc[mt][nt][e];
                    unsigned short hb = f2bf(v);
                    sh[A + i*A + j] = hb;
                    sl[A + i*A + j] = f2bf(v - bf2f(hb));
                }
            }
        }
}

// ---------------------------------------------------------------------------
// Kernel W: W[k][o] fp32 -> Wt_hi/Wt_lo[o][KP] bf16 (transposed, split).
// ---------------------------------------------------------------------------
__global__ __launch_bounds__(256) void wconv_kernel(
    const float* __restrict__ W,
    unsigned short* __restrict__ wt_hi, unsigned short* __restrict__ wt_lo)
{
    __shared__ float ls[64][65];
    const int tid = threadIdx.x;
    const int k0 = blockIdx.x * 64;
    const int o0 = blockIdx.y * 64;

    #pragma unroll
    for (int p = 0; p < 16; ++p) {
        int idx = tid + p*256;
        int kk = idx >> 6, oo = idx & 63;
        int k = k0 + kk;
        ls[kk][oo] = (k < SIG_CH) ? W[(long)k*OUT + o0 + oo] : 0.f;
    }
    __syncthreads();

    const int oo = tid >> 2;
    const int kq = (tid & 3) * 16;
    unsigned short hbuf[16], lbuf[16];
    #pragma unroll
    for (int j = 0; j < 16; ++j) {
        float v = ls[kq + j][oo];
        unsigned short hb = f2bf(v);
        hbuf[j] = hb;
        lbuf[j] = f2bf(v - bf2f(hb));
    }
    long off = (long)(o0 + oo)*KP + k0 + kq;
    *(ushort8*)(wt_hi + off)     = *(ushort8*)&hbuf[0];
    *(ushort8*)(wt_hi + off + 8) = *(ushort8*)&hbuf[8];
    *(ushort8*)(wt_lo + off)     = *(ushort8*)&lbuf[0];
    *(ushort8*)(wt_lo + off + 8) = *(ushort8*)&lbuf[8];
}

// ---------------------------------------------------------------------------
// Kernel C: MFMA bf16 split GEMM. part[z] = sig * Wt^T over K-chunk.
// ---------------------------------------------------------------------------
#define SPLITK 61
#define KC 352
#define NSTEP (KC/32)   // 11
#define LDA 40

__global__ __launch_bounds__(256) void gemm_kernel(
    const unsigned short* __restrict__ sig_hi, const unsigned short* __restrict__ sig_lo,
    const unsigned short* __restrict__ wt_hi,  const unsigned short* __restrict__ wt_lo,
    float* __restrict__ part)
{
    __shared__ __align__(16) unsigned short Ah[128*LDA];
    __shared__ __align__(16) unsigned short Al[128*LDA];
    __shared__ __align__(16) unsigned short Bh[128*LDA];
    __shared__ __align__(16) unsigned short Bl[128*LDA];

    const int tid = threadIdx.x;
    const int o0 = blockIdx.x * 128;
    const int n0 = blockIdx.y * 128;
    const int z  = blockIdx.z;
    const int k0 = z * KC;

    const int lane = tid & 63;
    const int w    = tid >> 6;
    const int wm   = w & 1;
    const int wn   = w >> 1;
    const int frow = lane & 15;
    const int quad = lane >> 4;

    const int srow = tid >> 1;
    const int kh   = (tid & 1) * 16;

    const unsigned short* gAh = sig_hi + (long)(n0 + srow)*KP;
    const unsigned short* gAl = sig_lo + (long)(n0 + srow)*KP;
    const unsigned short* gBh = wt_hi  + (long)(o0 + srow)*KP;
    const unsigned short* gBl = wt_lo  + (long)(o0 + srow)*KP;

    ushort8 rah[2], ral[2], rbh[2], rbl[2];
    const ushort8 z8 = {0,0,0,0,0,0,0,0};

    #define GLOAD(s)                                                          \
        {                                                                     \
            int kb = k0 + (s)*32 + kh;                                        \
            if (kb < KP) {                                                    \
                rah[0] = *(const ushort8*)(gAh + kb);                         \
                rah[1] = *(const ushort8*)(gAh + kb + 8);                     \
                ral[0] = *(const ushort8*)(gAl + kb);                         \
                ral[1] = *(const ushort8*)(gAl + kb + 8);                     \
                rbh[0] = *(const ushort8*)(gBh + kb);                         \
                rbh[1] = *(const ushort8*)(gBh + kb + 8);                     \
                rbl[0] = *(const ushort8*)(gBl + kb);                         \
                rbl[1] = *(const ushort8*)(gBl + kb + 8);                     \
            } else {                                                          \
                rah[0]=z8; rah[1]=z8; ral[0]=z8; ral[1]=z8;                   \
                rbh[0]=z8; rbh[1]=z8; rbl[0]=z8; rbl[1]=z8;                   \
            }                                                                 \
        }

    #define LSTORE()                                                          \
        {                                                                     \
            int o = srow*LDA + kh;                                            \
            *(ushort8*)(Ah + o)     = rah[0];                                 \
            *(ushort8*)(Ah + o + 8) = rah[1];                                 \
            *(ushort8*)(Al + o)     = ral[0];                                 \
            *(ushort8*)(Al + o + 8) = ral[1];                                 \
            *(ushort8*)(Bh + o)     = rbh[0];                                 \
            *(ushort8*)(Bh + o + 8) = rbh[1];                                 \
            *(ushort8*)(Bl + o)     = rbl[0];                                 \
            *(ushort8*)(Bl + o + 8) = rbl[1];                                 \
        }

    floatx4 acc[4][4];
    #pragma unroll
    for (int i = 0; i < 4; ++i)
        #pragma unroll
        for (int j = 0; j < 4; ++j)
            acc[i][j] = (floatx4){0.f, 0.f, 0.f, 0.f};

    GLOAD(0);
    LSTORE();
    __syncthreads();

    for (int s = 0; s < NSTEP; ++s) {
        if (s < NSTEP-1) GLOAD(s+1);

        short8 afh[4], afl[4], bfh[4], bfl[4];
        const int aoff = (wm*64 + frow)*LDA + quad*8;
        const int boff = (wn*64 + frow)*LDA + quad*8;
        #pragma unroll
        for (int tI = 0; tI < 4; ++tI) {
            afh[tI] = *(const short8*)(Ah + aoff + tI*16*LDA);
            afl[tI] = *(const short8*)(Al + aoff + tI*16*LDA);
            bfh[tI] = *(const short8*)(Bh + boff + tI*16*LDA);
            bfl[tI] = *(const short8*)(Bl + boff + tI*16*LDA);
        }
        #pragma unroll
        for (int mt = 0; mt < 4; ++mt)
            #pragma unroll
            for (int nt = 0; nt < 4; ++nt) {
                acc[mt][nt] = __builtin_amdgcn_mfma_f32_16x16x32_bf16(
                    afh[mt], bfh[nt], acc[mt][nt], 0, 0, 0);
                acc[mt][nt] = __builtin_amdgcn_mfma_f32_16x16x32_bf16(
                    afh[mt], bfl[nt], acc[mt][nt], 0, 0, 0);
                acc[mt][nt] = __builtin_amdgcn_mfma_f32_16x16x32_bf16(
                    afl[mt], bfh[nt], acc[mt][nt], 0, 0, 0);
            }
        __syncthreads();
        if (s < NSTEP-1) {
            LSTORE();
            __syncthreads();
        }
    }

    float* pz = part + (long)z * (Nn*OUT);
    #pragma unroll
    for (int mt = 0; mt < 4; ++mt)
        #pragma unroll
        for (int nt = 0; nt < 4; ++nt) {
            int col = o0 + wn*64 + nt*16 + frow;
            int rbase = n0 + wm*64 + mt*16 + quad*4;
            #pragma unroll
            for (int e = 0; e < 4; ++e)
                pz[(long)(rbase + e)*OUT + col] = acc[mt][nt][e];
        }
}

// ---------------------------------------------------------------------------
// Kernel D: out[n][o] = lin_b[o] + sum_z part[z][n][o]
// ---------------------------------------------------------------------------
__global__ __launch_bounds__(256) void reduce_kernel(
    const float* __restrict__ part, const float* __restrict__ lb,
    float* __restrict__ out)
{
    int idx = blockIdx.x * 256 + threadIdx.x;
    float s = lb[idx & 255];
    #pragma unroll 8
    for (int z = 0; z < SPLITK; ++z)
        s += part[(long)z * (Nn*OUT) + idx];
    out[idx] = s;
}

// ---------------------------------------------------------------------------
extern "C" void kernel_launch(void* const* d_in, const int* in_sizes, int n_in,
                              void* d_out, int out_size, void* d_ws, size_t ws_size,
                              hipStream_t stream) {
    const float* q  = (const float*)d_in[0];
    const float* w1 = (const float*)d_in[4];
    const float* b1 = (const float*)d_in[5];
    const float* w2 = (const float*)d_in[6];
    const float* b2 = (const float*)d_in[7];
    const float* lw = (const float*)d_in[8];
    const float* lb = (const float*)d_in[9];
    float* out = (float*)d_out;

    // ws layout (peak 59.71 MB):
    //   [0]          sig_hi  (256*KP*2 = 10,846,208)
    //   [10846208]   sig_lo  (10,846,208)
    //   [21692416]   aug_t fp32 [256][145][256] (38,010,880) -- dead after sig:
    //     [21692416] wt_hi (10,846,208)
    //     [32538624] wt_lo (10,846,208)
    //     [43384832] part  (61*65536*4 = 15,990,784)  (ends 59,375,616)
    char* ws = (char*)d_ws;
    unsigned short* sig_hi = (unsigned short*)ws;
    unsigned short* sig_lo = (unsigned short*)(ws + 10846208);
    float*          aug_t  = (float*)(ws + 21692416);
    unsigned short* wt_hi  = (unsigned short*)(ws + 21692416);
    unsigned short* wt_lo  = (unsigned short*)(ws + 32538624);
    float*          part   = (float*)(ws + 43384832);

    aug_kernel<<<dim3(4, Nn), 256, 0, stream>>>(q, w1, b1, w2, b2, aug_t);
    sig_kernel<<<Nn, 256, 0, stream>>>(aug_t, sig_hi, sig_lo);
    wconv_kernel<<<dim3(KP/64, OUT/64), 256, 0, stream>>>(lw, wt_hi, wt_lo);
    gemm_kernel<<<dim3(2, 2, SPLITK), 256, 0, stream>>>(sig_hi, sig_lo, wt_hi, wt_lo, part);
    reduce_kernel<<<(Nn*OUT)/256, 256, 0, stream>>>(part, lb, out);
}